// Round 10
// baseline (72.705 us; speedup 1.0000x reference)
//
#include <hip/hip_runtime.h>
#include <hip/hip_bf16.h>

// MoE: D=1024, H=1024, E=8, K=2; T=1024 tokens, N=2048 dispatch rows.
#define DM 1024
#define HD 1024
#define NE 8
#define NT 1024
#define NR 2048
#define BM 64
#define BN 64
#define BKK 64
#define LDK 72          // fallback GEMM only
#define MT_MAX 40
#define PN_MAX (MT_MAX * BM)       // 2560 padded rows
#define NBLK (MT_MAX * (HD / BN))  // 640 GEMM blocks
#define NXCD 8

typedef __attribute__((ext_vector_type(8))) short short8;
typedef __attribute__((ext_vector_type(4))) float f32x4;

typedef const __attribute__((address_space(1))) void* gas_ptr;
typedef __attribute__((address_space(3))) void* las_ptr;

__device__ __forceinline__ void glds16(const void* g, void* l) {
    __builtin_amdgcn_global_load_lds((gas_ptr)g, (las_ptr)l, 16, 0, 0);
}

#define WAITV(n) asm volatile("s_waitcnt vmcnt(" #n ")" ::: "memory")
#define SB() __builtin_amdgcn_sched_barrier(0)

__device__ __forceinline__ float gelu_tanh(float x) {
    float x3 = x * x * x;
    return 0.5f * x * (1.0f + tanhf(0.7978845608028654f * (x + 0.044715f * x3)));
}

// ---------------- router: one wave per token ----------------
__global__ void moe_router(const float* __restrict__ x, const float* __restrict__ rw,
                           int* __restrict__ e_sel, float* __restrict__ p_sel) {
    int t = blockIdx.x;
    int lane = threadIdx.x;
    const float* xr = x + (size_t)t * DM;
    float acc[NE];
#pragma unroll
    for (int e = 0; e < NE; ++e) acc[e] = 0.0f;
    for (int d = lane; d < DM; d += 64) {
        float xv = xr[d];
        const float* r = rw + (size_t)d * NE;
#pragma unroll
        for (int e = 0; e < NE; ++e) acc[e] += xv * r[e];
    }
#pragma unroll
    for (int e = 0; e < NE; ++e) {
#pragma unroll
        for (int off = 32; off > 0; off >>= 1) acc[e] += __shfl_xor(acc[e], off);
    }
    if (lane == 0) {
        float m = acc[0];
#pragma unroll
        for (int e = 1; e < NE; ++e) m = fmaxf(m, acc[e]);
        float p[NE];
        float s = 0.0f;
#pragma unroll
        for (int e = 0; e < NE; ++e) { p[e] = __expf(acc[e] - m); s += p[e]; }
        float inv = 1.0f / s;
        int i0 = 0;
#pragma unroll
        for (int e = 1; e < NE; ++e) if (p[e] > p[i0]) i0 = e;
        int i1 = (i0 == 0) ? 1 : 0;
#pragma unroll
        for (int e = 0; e < NE; ++e) if (e != i1 && e != i0 && p[e] > p[i1]) i1 = e;
        e_sel[2 * t + 0] = i0;
        e_sel[2 * t + 1] = i1;
        p_sel[2 * t + 0] = p[i0] * inv;
        p_sel[2 * t + 1] = p[i1] * inv;
    }
}

// ---------------- fused setup+scatter: single block ----------------
__global__ void moe_route_pack(const int* __restrict__ e_sel, int* __restrict__ meta,
                               int* __restrict__ sorted_tok, int* __restrict__ pos_of_row) {
    __shared__ int scnt[NE];
    __shared__ int soff[NE];
    int tid = threadIdx.x;
    if (tid < NE) scnt[tid] = 0;
    __syncthreads();
    for (int i = tid; i < NR; i += 256) atomicAdd(&scnt[e_sel[i]], 1);
    __syncthreads();
    if (tid == 0) {
        int off = 0, tc = 0;
        for (int e = 0; e < NE; ++e) {
            soff[e] = off;
            meta[8 + e] = off;
            int nt = (scnt[e] + BM - 1) / BM;
            for (int t = 0; t < nt; ++t) meta[16 + tc++] = e;
            off += nt * BM;
            scnt[e] = 0;
        }
        for (; tc < MT_MAX; ++tc) meta[16 + tc] = -1;
    }
    __syncthreads();
    for (int i = tid; i < PN_MAX; i += 256) sorted_tok[i] = -1;
    __syncthreads();
    for (int i = tid; i < NR; i += 256) {
        int e = e_sel[i];
        int r = atomicAdd(&scnt[e], 1);
        int pos = soff[e] + r;
        sorted_tok[pos] = i >> 1;
        pos_of_row[i] = pos;
    }
}

// ---------------- gather x (fp32) -> xg (bf16) at sorted positions ----------------
__global__ __launch_bounds__(256) void moe_gather(const float* __restrict__ x,
                                                  const int* __restrict__ sorted_tok,
                                                  __hip_bfloat16* __restrict__ xg) {
    int pos = blockIdx.x;
    int t = sorted_tok[pos];
    int j = threadIdx.x * 4;
    ushort4 u;
    if (t >= 0) {
        float4 f = *(const float4*)(x + (size_t)t * DM + j);
        __hip_bfloat16 b0 = __float2bfloat16(f.x), b1 = __float2bfloat16(f.y);
        __hip_bfloat16 b2 = __float2bfloat16(f.z), b3 = __float2bfloat16(f.w);
        u.x = *(unsigned short*)&b0; u.y = *(unsigned short*)&b1;
        u.z = *(unsigned short*)&b2; u.w = *(unsigned short*)&b3;
    } else {
        u.x = u.y = u.z = u.w = 0;
    }
    *(ushort4*)((unsigned short*)xg + (size_t)pos * DM + j) = u;
}

// ---------------- async grouped GEMM, fp32 W consumed directly ----------------
// A: bf16 row-major via glds16 depth-3 + XOR swizzle (exact r5 path).
// B: W fp32 [K][N]; each thread loads a 4k x 4n micro-tile (coalesced float4 rows),
//    converts to bf16, writes 8B (4 consecutive k per n) into the same swizzled
//    B^T layout the r5 MFMA reads. Reg double-buffer; compiler-tracked waits for
//    breg deps; hand vmcnt ONLY for A-glds with sched_barrier-pinned issue order.
// EPI=0: H=gelu(AW+b) bf16 row-major.  EPI=1: Y=AW+b fp32 row-major.
template <int EPI>
__global__ __launch_bounds__(256, 3) void moe_gemm_fused(const __hip_bfloat16* __restrict__ A,
                                                         const float* __restrict__ W,
                                                         const float* __restrict__ bias,
                                                         const int* __restrict__ meta,
                                                         __hip_bfloat16* __restrict__ Hout,
                                                         float* __restrict__ Yout) {
    int bid = blockIdx.x;
    int swz = (bid % NXCD) * (NBLK / NXCD) + bid / NXCD;
    int mt = swz >> 4;
    int nb = swz & 15;
    int e = meta[16 + mt];
    if (e < 0) return;

    __shared__ __align__(16) unsigned char smA[3 * 8192];  // depth-3 A
    __shared__ __align__(16) unsigned char smB[2 * 8192];  // depth-2 B (bf16, swizzled B^T)

    int tid = threadIdx.x;
    int wid = tid >> 6, lane = tid & 63;
    int wm = wid >> 1, wn = wid & 1;

    const unsigned short* Ab = (const unsigned short*)A + (size_t)mt * BM * DM;
    const float* Wb = W + (size_t)e * DM * HD + nb * BN;

    // --- A staging (r5-exact) ---
    int srow = wid * 16 + (lane >> 3);
    int s_log = (lane & 7) ^ (lane >> 3);
    const unsigned short* agp0 = Ab + (size_t)srow * DM + s_log * 8;
    const unsigned short* agp1 = agp0 + 8 * DM;
    auto ISSUE_A = [&](int b, int kt) {
        unsigned char* sa = &smA[b * 8192 + wid * 2048];
        glds16(agp0 + kt * BKK, sa);
        glds16(agp1 + kt * BKK, sa + 1024);
    };

    // --- B staging: 4k x 4n micro-tile per thread ---
    int kb4 = (tid >> 4) * 4;       // local k base (0..60)
    int nb4 = (tid & 15) * 4;       // local n base (0..60)
    const float* bgp = Wb + (size_t)kb4 * HD + nb4;
    f32x4 breg[2][4];
    auto LOAD_B = [&](int kt, int s) {
#pragma unroll
        for (int i = 0; i < 4; ++i)
            breg[s][i] = *(const f32x4*)(bgp + (size_t)(kt * BKK + i) * HD);
    };
    // write byte(row=n, k) = n*128 + (((k>>3) ^ (n&7))<<4) + (k&7)*2; kb4%4==0 -> 8B aligned
    auto WRITE_B = [&](int s) {
        unsigned char* base = &smB[s * 8192];
#pragma unroll
        for (int j = 0; j < 4; ++j) {
            int n = nb4 + j;
            __hip_bfloat16 c0 = __float2bfloat16(breg[s][0][j]);
            __hip_bfloat16 c1 = __float2bfloat16(breg[s][1][j]);
            __hip_bfloat16 c2 = __float2bfloat16(breg[s][2][j]);
            __hip_bfloat16 c3 = __float2bfloat16(breg[s][3][j]);
            unsigned int lo = (unsigned int)(*(unsigned short*)&c0) |
                              ((unsigned int)(*(unsigned short*)&c1) << 16);
            unsigned int hi = (unsigned int)(*(unsigned short*)&c2) |
                              ((unsigned int)(*(unsigned short*)&c3) << 16);
            uint2 u = {lo, hi};
            int byte = n * 128 + ((((kb4 >> 3) & 7) ^ (n & 7)) << 4) + ((kb4 & 7) * 2);
            *(uint2*)(base + byte) = u;
        }
    };

    // --- fragment read offsets (r5-exact swizzle) ---
    int r16 = lane & 15, g = lane >> 4, l7 = lane & 7;
    int aoff[2][2], boff[2][2];
#pragma unroll
    for (int kk = 0; kk < 2; ++kk)
#pragma unroll
        for (int f = 0; f < 2; ++f) {
            int sw = (((kk << 2) + g) ^ l7) << 4;
            aoff[kk][f] = (wm * 32 + r16 + 16 * f) * 128 + sw;
            boff[kk][f] = (wn * 32 + r16 + 16 * f) * 128 + sw;
        }

    f32x4 acc[2][2] = {};

    // prologue (issue order pinned; vmcnt ledger assumes B0 B1 A0 A1 A2)
    LOAD_B(0, 0); SB();
    LOAD_B(1, 1); SB();
    ISSUE_A(0, 0); SB();
    ISSUE_A(1, 1); SB();
    ISSUE_A(2, 2); SB();
    WRITE_B(0);           // compiler auto-waits on breg[0] deps
    SB();

#pragma unroll
    for (int kt = 0; kt < 16; ++kt) {
        // wait for A(kt) staged (2 glds). Ops issued after A(kt), pinned order:
        // kt=0:4  kt=1:8  kt=2..13:12  kt=14:10  kt=15:4
        if (kt == 0)       WAITV(4);
        else if (kt == 1)  WAITV(8);
        else if (kt == 14) WAITV(10);
        else if (kt == 15) WAITV(4);
        else               WAITV(12);
        asm volatile("s_waitcnt lgkmcnt(0)" ::: "memory");  // own ds_writes committed
        asm volatile("s_barrier" ::: "memory");
        const unsigned char* sa = &smA[(kt % 3) * 8192];
        const unsigned char* sb = &smB[(kt & 1) * 8192];
#pragma unroll
        for (int kk = 0; kk < 2; ++kk) {
            short8 a0 = *(const short8*)(sa + aoff[kk][0]);
            short8 a1 = *(const short8*)(sa + aoff[kk][1]);
            short8 b0 = *(const short8*)(sb + boff[kk][0]);
            short8 b1 = *(const short8*)(sb + boff[kk][1]);
            acc[0][0] = __builtin_amdgcn_mfma_f32_16x16x32_bf16(a0, b0, acc[0][0], 0, 0, 0);
            acc[0][1] = __builtin_amdgcn_mfma_f32_16x16x32_bf16(a0, b1, acc[0][1], 0, 0, 0);
            acc[1][0] = __builtin_amdgcn_mfma_f32_16x16x32_bf16(a1, b0, acc[1][0], 0, 0, 0);
            acc[1][1] = __builtin_amdgcn_mfma_f32_16x16x32_bf16(a1, b1, acc[1][1], 0, 0, 0);
        }
        asm volatile("s_barrier" ::: "memory");
        // tail: pinned order [B(kt+2) loads][A(kt+3) glds][WRITE_B(kt+1)]
        if (kt + 2 < 16) LOAD_B(kt + 2, kt & 1);
        SB();
        if (kt + 3 < 16) ISSUE_A(kt % 3, kt + 3);
        SB();
        if (kt + 1 < 16) WRITE_B((kt + 1) & 1);  // auto-waits on breg[(kt+1)&1]
        SB();
    }

    // epilogue: C/D layout col=lane&15, row=(lane>>4)*4+r
    int row0 = mt * BM + wm * 32 + ((lane >> 4) << 2);
    int col0 = nb * BN + wn * 32 + (lane & 15);
    const float* be = bias + (size_t)e * HD;
#pragma unroll
    for (int fm = 0; fm < 2; ++fm) {
#pragma unroll
        for (int fn = 0; fn < 2; ++fn) {
            int c = col0 + fn * 16;
            float bv = be[c];
#pragma unroll
            for (int r = 0; r < 4; ++r) {
                int rr = row0 + fm * 16 + r;
                float v = acc[fm][fn][r] + bv;
                if (EPI == 0) {
                    Hout[(size_t)rr * HD + c] = __float2bfloat16(gelu_tanh(v));
                } else {
                    Yout[(size_t)rr * HD + c] = v;
                }
            }
        }
    }
}

// ---------------- combine: out[t] = p0*y[pos0] + p1*y[pos1] ----------------
__global__ __launch_bounds__(256) void moe_combine(const float* __restrict__ y,
                                                   const float* __restrict__ p_sel,
                                                   const int* __restrict__ pos_of_row,
                                                   float* __restrict__ out) {
    int t = blockIdx.x;
    int j = threadIdx.x * 4;
    int q0 = pos_of_row[2 * t], q1 = pos_of_row[2 * t + 1];
    float p0 = p_sel[2 * t], p1 = p_sel[2 * t + 1];
    float4 a = *(const float4*)(y + (size_t)q0 * DM + j);
    float4 b = *(const float4*)(y + (size_t)q1 * DM + j);
    float4 o;
    o.x = p0 * a.x + p1 * b.x;
    o.y = p0 * a.y + p1 * b.y;
    o.z = p0 * a.z + p1 * b.z;
    o.w = p0 * a.w + p1 * b.w;
    *(float4*)(out + (size_t)t * DM + j) = o;
}

// ---------------- fallback GEMM (r2-style, lockstep, in-kernel conversion) ----------------
template <int EPI>
__global__ __launch_bounds__(256) void moe_gemm(const __hip_bfloat16* __restrict__ A,
                                                const float* __restrict__ W,
                                                const float* __restrict__ bias,
                                                const int* __restrict__ meta,
                                                __hip_bfloat16* __restrict__ Hout,
                                                float* __restrict__ Yout) {
    int mt = blockIdx.y;
    int e = meta[16 + mt];
    if (e < 0) return;
    int nb = blockIdx.x;
    __shared__ __align__(16) __hip_bfloat16 As[2][BM][LDK];
    __shared__ __align__(16) __hip_bfloat16 Bs[2][BN][LDK];
    int tid = threadIdx.x;
    int wid = tid >> 6, lane = tid & 63;
    int wm = wid >> 1, wn = wid & 1;
    const __hip_bfloat16* Ab = A + (size_t)mt * BM * DM;
    const float* Wb = W + (size_t)e * DM * HD + (size_t)nb * BN;
    uint4 ra[2];
    float4 rb[4];
    auto GLOAD = [&](int kt) {
#pragma unroll
        for (int i = 0; i < 2; ++i) {
            int c = tid + 256 * i;
            int row = c >> 3, col8 = c & 7;
            ra[i] = *(const uint4*)((const unsigned short*)Ab + (size_t)row * DM + kt * BKK + col8 * 8);
        }
#pragma unroll
        for (int i = 0; i < 4; ++i) {
            int c = tid + 256 * i;
            int kr = c >> 4, c4 = c & 15;
            rb[i] = *(const float4*)(Wb + (size_t)(kt * BKK + kr) * HD + c4 * 4);
        }
    };
    auto STORE = [&](int b) {
#pragma unroll
        for (int i = 0; i < 2; ++i) {
            int c = tid + 256 * i;
            int row = c >> 3, col8 = c & 7;
            *(uint4*)&As[b][row][col8 * 8] = ra[i];
        }
#pragma unroll
        for (int i = 0; i < 4; ++i) {
            int c = tid + 256 * i;
            int kr = c >> 4, c4 = c & 15;
            Bs[b][c4 * 4 + 0][kr] = __float2bfloat16(rb[i].x);
            Bs[b][c4 * 4 + 1][kr] = __float2bfloat16(rb[i].y);
            Bs[b][c4 * 4 + 2][kr] = __float2bfloat16(rb[i].z);
            Bs[b][c4 * 4 + 3][kr] = __float2bfloat16(rb[i].w);
        }
    };
    f32x4 acc[2][2] = {};
    GLOAD(0);
    STORE(0);
    __syncthreads();
    int buf = 0;
    const int NK = DM / BKK;
    for (int kt = 0; kt < NK; ++kt) {
        if (kt + 1 < NK) GLOAD(kt + 1);
#pragma unroll
        for (int kk = 0; kk < 2; ++kk) {
            int kb = kk * 32 + (lane >> 4) * 8;
            short8 a0 = *(const short8*)&As[buf][wm * 32 + (lane & 15)][kb];
            short8 a1 = *(const short8*)&As[buf][wm * 32 + 16 + (lane & 15)][kb];
            short8 b0 = *(const short8*)&Bs[buf][wn * 32 + (lane & 15)][kb];
            short8 b1 = *(const short8*)&Bs[buf][wn * 32 + 16 + (lane & 15)][kb];
            acc[0][0] = __builtin_amdgcn_mfma_f32_16x16x32_bf16(a0, b0, acc[0][0], 0, 0, 0);
            acc[0][1] = __builtin_amdgcn_mfma_f32_16x16x32_bf16(a0, b1, acc[0][1], 0, 0, 0);
            acc[1][0] = __builtin_amdgcn_mfma_f32_16x16x32_bf16(a1, b0, acc[1][0], 0, 0, 0);
            acc[1][1] = __builtin_amdgcn_mfma_f32_16x16x32_bf16(a1, b1, acc[1][1], 0, 0, 0);
        }
        if (kt + 1 < NK) {
            STORE(buf ^ 1);
            __syncthreads();
            buf ^= 1;
        }
    }
    int row0 = mt * BM + wm * 32 + ((lane >> 4) << 2);
    int col0 = nb * BN + wn * 32 + (lane & 15);
    const float* be = bias + (size_t)e * HD;
#pragma unroll
    for (int fm = 0; fm < 2; ++fm) {
#pragma unroll
        for (int fn = 0; fn < 2; ++fn) {
            int c = col0 + fn * 16;
            float bv = be[c];
#pragma unroll
            for (int r = 0; r < 4; ++r) {
                int rr = row0 + fm * 16 + r;
                float v = acc[fm][fn][r] + bv;
                if (EPI == 0) {
                    Hout[(size_t)rr * HD + c] = __float2bfloat16(gelu_tanh(v));
                } else {
                    Yout[(size_t)rr * HD + c] = v;
                }
            }
        }
    }
}

extern "C" void kernel_launch(void* const* d_in, const int* in_sizes, int n_in,
                              void* d_out, int out_size, void* d_ws, size_t ws_size,
                              hipStream_t stream) {
    const float* x     = (const float*)d_in[0];
    const float* rw    = (const float*)d_in[1];
    const float* w_in  = (const float*)d_in[2];
    const float* b_in  = (const float*)d_in[3];
    const float* w_out = (const float*)d_in[4];
    const float* b_out = (const float*)d_in[5];
    float* out = (float*)d_out;

    char* ws = (char*)d_ws;
    int*   e_sel      = (int*)ws;
    float* p_sel      = (float*)(ws + 8 * 1024);
    int*   meta       = (int*)(ws + 16 * 1024);
    int*   sorted_tok = (int*)(ws + 17 * 1024);
    int*   pos_of_row = (int*)(ws + 27 * 1024);

    const size_t SZ_X = (size_t)PN_MAX * DM * 2;   // 5.24 MB (xg or h, bf16)
    const size_t SZ_Y = (size_t)PN_MAX * DM * 4;   // 10.49 MB (y fp32)

    __hip_bfloat16* xg = (__hip_bfloat16*)(ws + 64 * 1024);
    __hip_bfloat16* h  = (__hip_bfloat16*)(ws + 64 * 1024 + SZ_X);
    float*          y  = (float*)(ws + 64 * 1024 + 2 * SZ_X);

    const size_t NEED = 64 * 1024 + 2 * SZ_X + SZ_Y;  // ~21.1 MB

    moe_router<<<NT, 64, 0, stream>>>(x, rw, e_sel, p_sel);
    moe_route_pack<<<1, 256, 0, stream>>>(e_sel, meta, sorted_tok, pos_of_row);
    moe_gather<<<PN_MAX, 256, 0, stream>>>(x, sorted_tok, xg);
    if (ws_size >= NEED) {
        moe_gemm_fused<0><<<NBLK, 256, 0, stream>>>(xg, w_in, b_in, meta, h, nullptr);
        moe_gemm_fused<1><<<NBLK, 256, 0, stream>>>(h, w_out, b_out, meta, nullptr, y);
    } else {
        dim3 grid(HD / BN, MT_MAX);
        moe_gemm<0><<<grid, 256, 0, stream>>>(xg, w_in, b_in, meta, h, nullptr);
        moe_gemm<1><<<grid, 256, 0, stream>>>(h, w_out, b_out, meta, nullptr, y);
    }
    moe_combine<<<NT, 256, 0, stream>>>(y, p_sel, pos_of_row, out);
}